// Round 4
// baseline (322.253 us; speedup 1.0000x reference)
//
#include <hip/hip_runtime.h>

#define B_  8
#define C_  128
#define H_  128
#define W_  256
#define HW_ (H_ * W_)
#define TH  16
#define TW  32
#define S2S 44                   // padded f2 row stride (dwords), mult of 4
#define S1S 36                   // padded f1 row stride (dwords), mult of 4
#define S1OFF (24 * S2S)         // 1056 (f2 tile = 24 rows)
#define PAIRN (S1OFF + TH * S1S) // 1632 dwords per channel-pair tile
#define NTHREADS 576

typedef __fp16 h2 __attribute__((ext_vector_type(2)));

__device__ __forceinline__ float dot2f16(unsigned int a, unsigned int b, float c) {
#if __has_builtin(__builtin_amdgcn_fdot2)
    return __builtin_amdgcn_fdot2(__builtin_bit_cast(h2, a),
                                  __builtin_bit_cast(h2, b), c, false);
#else
    h2 ha = __builtin_bit_cast(h2, a), hb = __builtin_bit_cast(h2, b);
    return c + (float)ha.x * (float)hb.x + (float)ha.y * (float)hb.y;
#endif
}

__device__ __forceinline__ unsigned int pk(float x, float y) {
    h2 r = __builtin_amdgcn_cvt_pkrtz(x, y);
    return __builtin_bit_cast(unsigned int, r);
}

// 9-wave block, wave = di. Depth-2 software pipeline:
//   loads for stage s+2 issued before compute of stage s; LDS write of s+1
//   waits only its own loads (counted vmcnt); barriers are raw s_barrier with
//   lgkmcnt(0) only -> global loads stay in flight across barriers.
// Stage = 4 channels. LDS dword = f16x2 {ch c, ch c+1} of one pixel.
__global__ __launch_bounds__(NTHREADS, 3) void cv_kernel(
    const float* __restrict__ f1g, const float* __restrict__ f2g,
    float* __restrict__ outg) {
    __shared__ __align__(16) unsigned int lds[2][2][PAIRN];

    const int tid = threadIdx.x;
    const int w0 = blockIdx.x * TW;
    const int h0 = blockIdx.y * TH;
    const int b  = blockIdx.z;

    // ---- staging slots ----
    // slot0 (all 576): tid<480 -> f2 tile 24 rows x 10 float4-cols x 2 pairs
    //                  tid>=480 -> f1 rows 0..5 (96 slots)
    // slot1 (tid<160): f1 rows 6..15 (160 slots)
    int off0, off1 = 0, ld0, ld1 = 0, pp, pd = 0;
    float m0;
    const float* p0;
    const bool dual = (tid < 160);
    if (tid < 480) {
        int r  = tid / 20, u = tid % 20;
        pp = u / 10;
        int c4 = u % 10;
        int gh = h0 - 4 + r, gw = w0 - 4 + 4 * c4;
        bool valid = (gh >= 0) && (gh < H_) && (gw >= 0) && (gw <= W_ - 4);
        int ghc = min(max(gh, 0), H_ - 1);
        int gwc = min(max(gw, 0), W_ - 4);
        off0 = ((b * C_ + 2 * pp) * H_ + ghc) * W_ + gwc;
        p0   = f2g;
        ld0  = r * S2S + 4 * c4;
        m0   = valid ? 1.f : 0.f;
    } else {
        int s = tid - 480;                 // 0..95 -> f1 rows 0..5
        int r = s / 16, u = s % 16;
        pp = u / 8;
        int c4 = u % 8;
        off0 = ((b * C_ + 2 * pp) * H_ + h0 + r) * W_ + w0 + 4 * c4;
        p0   = f1g;
        ld0  = S1OFF + r * S1S + 4 * c4;
        m0   = 1.f;
    }
    if (dual) {
        int s = 96 + tid;                  // 96..255 -> f1 rows 6..15
        int r = s / 16, u = s % 16;
        pd = u / 8;
        int c4 = u % 8;
        off1 = ((b * C_ + 2 * pd) * H_ + h0 + r) * W_ + w0 + 4 * c4;
        ld1  = S1OFF + r * S1S + 4 * c4;
    }

#define LOADST(Sa, Sb, Sc, Sd)                                                \
    do {                                                                      \
        Sa = *(const float4*)(p0 + off0);                                     \
        Sb = *(const float4*)(p0 + off0 + HW_);                               \
        off0 += 4 * HW_;                                                      \
        if (dual) {                                                           \
            Sc = *(const float4*)(f1g + off1);                                \
            Sd = *(const float4*)(f1g + off1 + HW_);                          \
            off1 += 4 * HW_;                                                  \
        }                                                                     \
    } while (0)

#define STOREST(bi, Sa, Sb, Sc, Sd)                                           \
    do {                                                                      \
        uint4 wv;                                                             \
        wv.x = pk(Sa.x * m0, Sb.x * m0);                                      \
        wv.y = pk(Sa.y * m0, Sb.y * m0);                                      \
        wv.z = pk(Sa.z * m0, Sb.z * m0);                                      \
        wv.w = pk(Sa.w * m0, Sb.w * m0);                                      \
        *(uint4*)(&lds[bi][pp][ld0]) = wv;                                    \
        if (dual) {                                                           \
            uint4 w2;                                                         \
            w2.x = pk(Sc.x, Sd.x);                                            \
            w2.y = pk(Sc.y, Sd.y);                                            \
            w2.z = pk(Sc.z, Sd.z);                                            \
            w2.w = pk(Sc.w, Sd.w);                                            \
            *(uint4*)(&lds[bi][pd][ld1]) = w2;                                \
        }                                                                     \
    } while (0)

#define BAR()                                                                 \
    do {                                                                      \
        asm volatile("s_waitcnt lgkmcnt(0)" ::: "memory");                    \
        __builtin_amdgcn_s_barrier();                                         \
    } while (0)

    // ---- compute mapping ----
    const int di   = tid >> 6;
    const int lane = tid & 63;
    const int hh   = lane >> 2;
    const int sc   = lane & 3;
    const int ww   = sc * 8;
    const int rdF2 = (hh + di) * S2S + ww;
    const int rdF1 = S1OFF + hh * S1S + ww;

    float acc[9][8];
#pragma unroll
    for (int j = 0; j < 9; ++j)
#pragma unroll
        for (int p = 0; p < 8; ++p) acc[j][p] = 0.f;

#define COMPUTE(bi)                                                           \
    do {                                                                      \
        _Pragma("unroll")                                                     \
        for (int q = 0; q < 2; ++q) {                                         \
            const unsigned int* buf = lds[bi][q];                             \
            uint4 fa = *(const uint4*)(buf + rdF2);                           \
            uint4 fb = *(const uint4*)(buf + rdF2 + 4);                       \
            uint4 fc = *(const uint4*)(buf + rdF2 + 8);                       \
            uint4 fd = *(const uint4*)(buf + rdF2 + 12);                      \
            uint4 ga = *(const uint4*)(buf + rdF1);                           \
            uint4 gb = *(const uint4*)(buf + rdF1 + 4);                       \
            unsigned int f2u[16] = {fa.x, fa.y, fa.z, fa.w, fb.x, fb.y,       \
                                    fb.z, fb.w, fc.x, fc.y, fc.z, fc.w,       \
                                    fd.x, fd.y, fd.z, fd.w};                  \
            unsigned int f1u[8]  = {ga.x, ga.y, ga.z, ga.w,                   \
                                    gb.x, gb.y, gb.z, gb.w};                  \
            _Pragma("unroll")                                                 \
            for (int j = 0; j < 9; ++j)                                       \
                _Pragma("unroll")                                             \
                for (int p = 0; p < 8; ++p)                                   \
                    acc[j][p] = dot2f16(f1u[p], f2u[p + j], acc[j][p]);       \
        }                                                                     \
    } while (0)

    float4 aA, bA, cA, dA, aB, bB, cB, dB;

    // prologue: stages 0,1 in flight; stage 0 into LDS buf0
    LOADST(aA, bA, cA, dA);            // stage 0
    LOADST(aB, bB, cB, dB);            // stage 1
    STOREST(0, aA, bA, cA, dA);        // waits stage-0 loads only
    BAR();

    for (int s = 0; s < 30; s += 2) {
        LOADST(aA, bA, cA, dA);        // stage s+2 (in flight through compute)
        COMPUTE(0);                    // stage s
        STOREST(1, aB, bB, cB, dB);    // stage s+1 (counted vmcnt)
        BAR();
        LOADST(aB, bB, cB, dB);        // stage s+3
        COMPUTE(1);                    // stage s+1
        STOREST(0, aA, bA, cA, dA);    // stage s+2
        BAR();
    }
    COMPUTE(0);                        // stage 30
    STOREST(1, aB, bB, cB, dB);        // stage 31
    BAR();
    COMPUTE(1);                        // stage 31

    // ---- epilogue: mean over C and store ----
    const float inv = 1.0f / 128.0f;
    int obase = ((b * 81 + di * 9) * H_ + h0 + hh) * W_ + w0 + ww;
#pragma unroll
    for (int j = 0; j < 9; ++j) {
        float4 o0 = make_float4(acc[j][0] * inv, acc[j][1] * inv,
                                acc[j][2] * inv, acc[j][3] * inv);
        float4 o1 = make_float4(acc[j][4] * inv, acc[j][5] * inv,
                                acc[j][6] * inv, acc[j][7] * inv);
        *(float4*)(outg + obase)     = o0;
        *(float4*)(outg + obase + 4) = o1;
        obase += HW_;
    }
}

extern "C" void kernel_launch(void* const* d_in, const int* in_sizes, int n_in,
                              void* d_out, int out_size, void* d_ws, size_t ws_size,
                              hipStream_t stream) {
    const float* f1 = (const float*)d_in[0];
    const float* f2 = (const float*)d_in[1];
    float* out = (float*)d_out;
    dim3 grid(W_ / TW, H_ / TH, B_);   // 8 x 8 x 8 = 512 blocks
    cv_kernel<<<grid, NTHREADS, 0, stream>>>(f1, f2, out);
}